// Round 11
// baseline (1208.840 us; speedup 1.0000x reference)
//
#include <hip/hip_runtime.h>

#define T_STEPS 128
#define BATCH   64
#define INDIM   512
#define HDIM    1024
#define NE      819
#define OUT0_SZ (T_STEPS*BATCH*HDIM)
#define BH      (BATCH*HDIM)          /* 65536 */
#define ALLH_L  (129*BH)

#define HS_LAY   131072               /* shorts per (slot,layer): hi 65536 + lo 65536 */
#define HS_SLOT  393216               /* shorts per slot (3 layers) */
#define NSLOT    131                  /* full-depth h ring: writes at s -> slot s+1 */
#define XF_T     65536                /* shorts per timestep of x-frags: hi 32768 + lo 32768 */
#define NBLK     192
#define NGRP     8
#define GSZ      24

typedef short bf16x8 __attribute__((ext_vector_type(8)));
typedef short short2v __attribute__((ext_vector_type(2)));
typedef float f32x4  __attribute__((ext_vector_type(4)));
typedef float f32x2  __attribute__((ext_vector_type(2)));

__device__ __forceinline__ short f2bf(float f){
    unsigned u = __float_as_uint(f);
    u += 0x7FFF + ((u >> 16) & 1);           /* RNE */
    return (short)(u >> 16);
}
__device__ __forceinline__ float bf2f(short s){
    return __uint_as_float(((unsigned)(unsigned short)s) << 16);
}

/* ============ one-time prep: weights -> |.|*sign*emask, split hi/lo, frag-swizzled ============ */
__global__ __launch_bounds__(256) void ei_prep_w(const float* __restrict__ Win0,
        const float* __restrict__ Win1, const float* __restrict__ Win2,
        const float* __restrict__ Wrec, short* __restrict__ wf){
    int gid = blockIdx.x * 256 + threadIdx.x;      /* 0 .. 720895 */
    int j, local, nkb, kff; const float* Win; short* base;
    if (gid < 196608)      { j=0; local=gid;        nkb=48; kff=512;  Win=Win0; base=wf; }
    else if (gid < 458752) { j=1; local=gid-196608; nkb=64; kff=1024; Win=Win1; base=wf+3145728; }
    else                   { j=2; local=gid-458752; nkb=64; kff=1024; Win=Win2; base=wf+7340032; }
    int lane = local & 63;
    int fi   = local >> 6;
    int kb   = fi % nkb;
    int it   = fi / nkb;
    int i    = it*16 + (lane & 15);
    int k0   = kb*32 + ((lane >> 4) << 3);
    const float* wrec_row = Wrec + ((size_t)j*HDIM + i)*HDIM;
    bf16x8 hv, lv;
    #pragma unroll
    for (int e = 0; e < 8; ++e){
        int k = k0 + e;
        float w;
        if (k < kff){
            w = fabsf(Win[(size_t)i*kff + k]);
            if (j != 0 && k >= NE) w = 0.f;
        } else {
            int kr = k - kff;
            w = fabsf(wrec_row[kr]);
            if (kr >= NE) w = -w;
        }
        short h = f2bf(w);
        hv[e] = h;
        lv[e] = f2bf(w - bf2f(h));
    }
    short* dst = base + (size_t)fi*1024 + lane*8;
    *(bf16x8*)dst         = hv;
    *(bf16x8*)(dst + 512) = lv;
}

/* ============ one-time prep: x -> A-frag layout [t][plane][kb(16)][bt(4)][lane(64)][8] ============ */
__global__ __launch_bounds__(256) void ei_prep_xf(const float* __restrict__ x,
        short* __restrict__ xf){
    int gid = blockIdx.x * 256 + threadIdx.x;      /* 0 .. 524287 */
    int lane = gid & 63;
    int bt   = (gid >> 6) & 3;
    int kb   = (gid >> 8) & 15;
    int t    = gid >> 12;
    int b = bt*16 + (lane & 15);
    int k = kb*32 + ((lane >> 4) << 3);
    const float* src = x + ((size_t)t*BATCH + b)*INDIM + k;
    float4 v0 = *(const float4*)src;
    float4 v1 = *(const float4*)(src + 4);
    float f[8] = {v0.x,v0.y,v0.z,v0.w,v1.x,v1.y,v1.z,v1.w};
    bf16x8 hv, lv;
    #pragma unroll
    for (int e = 0; e < 8; ++e){
        short h = f2bf(f[e]);
        hv[e] = h; lv[e] = f2bf(f[e] - bf2f(h));
    }
    short* dst = xf + (size_t)t*XF_T + (((size_t)(kb*4 + bt)) << 9) + lane*8;
    *(bf16x8*)dst            = hv;
    *(bf16x8*)(dst + 32768)  = lv;
}

/* ============ init: all_h[l][0]=h0, h-frag slot 0, barrier zero ============ */
__global__ __launch_bounds__(256) void ei_init5(const float* __restrict__ h0,
        float* __restrict__ out, short* __restrict__ hf, int* __restrict__ bar){
    int idx = blockIdx.x * 256 + threadIdx.x;      /* 0 .. 196607 */
    int l = idx >> 16, r = idx & 0xFFFF;
    out[OUT0_SZ + (size_t)l*ALLH_L + r] = h0[r];
    if (idx < 1024) bar[idx] = 0;
    if (idx < 24576){
        int lane = idx & 63, bt = (idx >> 6) & 3, kb = (idx >> 8) & 31, j = idx >> 13;
        int b = bt*16 + (lane & 15);
        int k = kb*32 + ((lane >> 4) << 3);
        const float* src = h0 + (size_t)b*HDIM + k;
        float4 v0 = *(const float4*)src;
        float4 v1 = *(const float4*)(src + 4);
        float f[8] = {v0.x,v0.y,v0.z,v0.w,v1.x,v1.y,v1.z,v1.w};
        bf16x8 hv, lv;
        #pragma unroll
        for (int e = 0; e < 8; ++e){
            short hh = f2bf(f[e]);
            hv[e] = hh; lv[e] = f2bf(f[e] - bf2f(hh));
        }
        int off = ((kb*4 + bt) << 9) + lane*8;
        short* b0 = hf + (size_t)j*HS_LAY + off;   /* slot 0 */
        *(bf16x8*)b0           = hv;
        *(bf16x8*)(b0 + 65536) = lv;
    }
}

/* ============ per-step GEMM body v3: FULL A-register hoist, W depth-2 (L2 hits) ======== */
template<int NKW, int NKFF, int FFLO>
__device__ __forceinline__ void step_mm3(
        const short* __restrict__ pff, const short* __restrict__ prec,
        const short* __restrict__ wp0, const short* __restrict__ wp1,
        int kb0, int btbase, int laneo, f32x4 acc[2][2])
{
    /* burst-issue ALL A fragments for this wave's K-slice */
    bf16x8 ah[NKW][2], al[NKW][2];
    #pragma unroll
    for (int kk = 0; kk < NKW; ++kk){
        int kb = kb0 + kk;
        const short* pa; int lo;
        if (kb < NKFF){ pa = pff + (kb << 11); lo = FFLO; }
        else          { pa = prec + ((kb - NKFF) << 11); lo = 65536; }
        ah[kk][0] = *(const bf16x8*)(pa + ((btbase + 0) << 9) + laneo);
        ah[kk][1] = *(const bf16x8*)(pa + ((btbase + 1) << 9) + laneo);
        al[kk][0] = *(const bf16x8*)(pa + lo + ((btbase + 0) << 9) + laneo);
        al[kk][1] = *(const bf16x8*)(pa + lo + ((btbase + 1) << 9) + laneo);
    }
    bf16x8 wh[2][2], wl[2][2];
    {
        const short* a = wp0 + (kb0 << 10);
        const short* b = wp1 + (kb0 << 10);
        wh[0][0] = *(const bf16x8*)a; wl[0][0] = *(const bf16x8*)(a + 512);
        wh[0][1] = *(const bf16x8*)b; wl[0][1] = *(const bf16x8*)(b + 512);
    }
    #pragma unroll
    for (int kk = 0; kk < NKW; ++kk){
        if (kk + 1 < NKW){
            const int nb = (kk + 1) & 1;
            const short* a = wp0 + ((kb0 + kk + 1) << 10);
            const short* b = wp1 + ((kb0 + kk + 1) << 10);
            wh[nb][0] = *(const bf16x8*)a; wl[nb][0] = *(const bf16x8*)(a + 512);
            wh[nb][1] = *(const bf16x8*)b; wl[nb][1] = *(const bf16x8*)(b + 512);
        }
        const int b2 = kk & 1;
        acc[0][0] = __builtin_amdgcn_mfma_f32_16x16x32_bf16(ah[kk][0], wh[b2][0], acc[0][0], 0,0,0);
        acc[0][1] = __builtin_amdgcn_mfma_f32_16x16x32_bf16(ah[kk][1], wh[b2][0], acc[0][1], 0,0,0);
        acc[1][0] = __builtin_amdgcn_mfma_f32_16x16x32_bf16(ah[kk][0], wh[b2][1], acc[1][0], 0,0,0);
        acc[1][1] = __builtin_amdgcn_mfma_f32_16x16x32_bf16(ah[kk][1], wh[b2][1], acc[1][1], 0,0,0);
        acc[0][0] = __builtin_amdgcn_mfma_f32_16x16x32_bf16(al[kk][0], wh[b2][0], acc[0][0], 0,0,0);
        acc[0][1] = __builtin_amdgcn_mfma_f32_16x16x32_bf16(al[kk][1], wh[b2][0], acc[0][1], 0,0,0);
        acc[1][0] = __builtin_amdgcn_mfma_f32_16x16x32_bf16(al[kk][0], wh[b2][1], acc[1][0], 0,0,0);
        acc[1][1] = __builtin_amdgcn_mfma_f32_16x16x32_bf16(al[kk][1], wh[b2][1], acc[1][1], 0,0,0);
        acc[0][0] = __builtin_amdgcn_mfma_f32_16x16x32_bf16(ah[kk][0], wl[b2][0], acc[0][0], 0,0,0);
        acc[0][1] = __builtin_amdgcn_mfma_f32_16x16x32_bf16(ah[kk][1], wl[b2][0], acc[0][1], 0,0,0);
        acc[1][0] = __builtin_amdgcn_mfma_f32_16x16x32_bf16(ah[kk][0], wl[b2][1], acc[1][0], 0,0,0);
        acc[1][1] = __builtin_amdgcn_mfma_f32_16x16x32_bf16(ah[kk][1], wl[b2][1], acc[1][1], 0,0,0);
    }
}

/* ============ persistent v5: r9 skeleton (two-level relaxed barrier, no fences,
   virgin-slot hf ring, sc0sc1 write-through h) + full A hoist + coalesced hf stores ===== */
__global__ __launch_bounds__(512, 2) void ei_persist5(
        const short* __restrict__ xf, const short* __restrict__ wf,
        const float* __restrict__ bias, float* __restrict__ out,
        short* __restrict__ hf, int* __restrict__ bar)
{
    const int bid   = blockIdx.x;
    const int g     = bid & 7;
    const int w     = bid >> 3;            /* 0..23 */
    const int j     = w >> 3;              /* 0..2 */
    const int strip = g*4 + ((w >> 1) & 3);/* 0..31 */
    const int bhalf = w & 1;
    const int grp   = g;

    const int tx    = threadIdx.x;
    const int wv    = tx >> 6, lane = tx & 63;
    const int laneo = lane * 8;
    const int btbase = bhalf * 2;
    const int it0   = strip * 2;

    const short* wfj = wf + (j == 0 ? 0 : (j == 1 ? 3145728 : 7340032));
    const int nkb  = (j == 0) ? 48 : 64;
    const int NKW  = nkb >> 3;
    const int kb0  = wv * NKW;
    const short* wp0 = wfj + it0*nkb*1024 + laneo;
    const short* wp1 = wp0 + nkb*1024;

    /* ---- epilogue mapping, frag-linear for coalesced hf stores ----
       thread tx -> frag elements (2*(tx&255), +1) of chunk (strip*4 + bhalf*2 + (tx>>8)).
       Verified: lnw*8+e0 == 2*(tx&255). */
    const int btl = tx >> 8;               /* 0..1 */
    const int q   = tx & 255;
    const int lnw = q >> 2;                /* 0..63 */
    const int e0  = (q & 3) * 2;           /* 0,2,4,6 */
    const int b_g = (bhalf*2 + btl)*16 + (lnw & 15);
    const int i_g = strip*32 + ((lnw >> 4) << 3) + e0;
    const int bl  = b_g & 31;              /* psum row (block-local batch) */
    const int il0 = ((lnw >> 4) << 3) + e0;/* psum col pair */
    const int hoff = ((strip*4 + bhalf*2 + btl) << 9) + q*2;   /* shorts */
    const f32x2 bb = *(const f32x2*)&bias[j*HDIM + i_g];
    f32x2 vreg = {0.f, 0.f};

    __shared__ float psum[8][32][34];

    for (int s = 0; s < T_STEPS + 2; ++s){
        const int t = s - j;
        const bool act = (t >= 0) && (t < T_STEPS);
        if (act){
            const short* hfr  = hf + (size_t)s*HS_SLOT;
            const short* prec = (t == 0) ? (hf + (size_t)j*HS_LAY)
                                         : (hfr + (size_t)j*HS_LAY);
            f32x4 acc[2][2] = {{{0.f,0.f,0.f,0.f},{0.f,0.f,0.f,0.f}},
                               {{0.f,0.f,0.f,0.f},{0.f,0.f,0.f,0.f}}};
            if (j == 0)
                step_mm3<6,16,32768>(xf + (size_t)t*XF_T, prec, wp0, wp1, kb0, btbase, laneo, acc);
            else if (j == 1)
                step_mm3<8,32,65536>(hfr, prec, wp0, wp1, kb0, btbase, laneo, acc);
            else
                step_mm3<8,32,65536>(hfr + HS_LAY, prec, wp0, wp1, kb0, btbase, laneo, acc);

            /* C/D layout: col=lane&15, row=(lane>>4)*4+r [m89] */
            const int r0 = (lane >> 4) << 2, l15 = lane & 15;
            #pragma unroll
            for (int ic = 0; ic < 2; ++ic)
                #pragma unroll
                for (int bt = 0; bt < 2; ++bt)
                    #pragma unroll
                    for (int r = 0; r < 4; ++r)
                        psum[wv][bt*16 + r0 + r][ic*16 + l15] = acc[ic][bt][r];
        }
        __syncthreads();
        if (act){
            float sum0 = 0.f, sum1 = 0.f;
            #pragma unroll
            for (int ww = 0; ww < 8; ++ww){
                f32x2 p = *(f32x2*)&psum[ww][bl][il0];
                sum0 += p[0]; sum1 += p[1];
            }
            vreg[0] = 0.8f*vreg[0] + 0.2f*(sum0 + bb[0]);
            vreg[1] = 0.8f*vreg[1] + 0.2f*(sum1 + bb[1]);
            float h0v = vreg[0] > 0.f ? vreg[0] : 0.f;
            float h1v = vreg[1] > 0.f ? vreg[1] : 0.f;
            f32x2 hv2 = {h0v, h1v};
            *(f32x2*)&out[OUT0_SZ + ((size_t)(j*129 + t + 1))*BH + b_g*HDIM + i_g] = hv2;
            if (j == 2){
                f32x2 o2 = {(i_g < NE) ? h0v : 0.f, (i_g + 1 < NE) ? h1v : 0.f};
                *(f32x2*)&out[(size_t)t*BH + b_g*HDIM + i_g] = o2;
            }
            /* h-frags: coalesced write-through (sc0 sc1) into virgin slot s+1 */
            short hh0 = f2bf(h0v), hl0 = f2bf(h0v - bf2f(hh0));
            short hh1 = f2bf(h1v), hl1 = f2bf(h1v - bf2f(hh1));
            int hi2 = (int)(unsigned short)hh0 | ((int)(unsigned short)hh1 << 16);
            int lo2 = (int)(unsigned short)hl0 | ((int)(unsigned short)hl1 << 16);
            short* hww = hf + (size_t)(s + 1)*HS_SLOT + (size_t)j*HS_LAY + hoff;
            asm volatile("global_store_dword %0, %1, off sc0 sc1"
                         :: "v"(hww), "v"(hi2) : "memory");
            asm volatile("global_store_dword %0, %1, off sc0 sc1"
                         :: "v"(hww + 65536), "v"(lo2) : "memory");
        }
        if (s == T_STEPS + 1) break;
        asm volatile("s_waitcnt vmcnt(0)" ::: "memory");
        __syncthreads();
        /* ---- relaxed two-level grid barrier (r9, proven) ---- */
        if (tx == 0){
            int prev = __hip_atomic_fetch_add(&bar[grp*32], 1,
                        __ATOMIC_RELAXED, __HIP_MEMORY_SCOPE_AGENT);
            if (prev == (s + 1)*GSZ - 1){
                int sp = __hip_atomic_fetch_add(&bar[256], 1,
                        __ATOMIC_RELAXED, __HIP_MEMORY_SCOPE_AGENT);
                if (sp == (s + 1)*NGRP - 1){
                    #pragma unroll
                    for (int gg = 0; gg < NGRP; ++gg)
                        __hip_atomic_store(&bar[512 + gg*32], s + 1,
                                __ATOMIC_RELAXED, __HIP_MEMORY_SCOPE_AGENT);
                }
            }
            while (__hip_atomic_load(&bar[512 + grp*32],
                    __ATOMIC_RELAXED, __HIP_MEMORY_SCOPE_AGENT) < s + 1)
                __builtin_amdgcn_s_sleep(1);
        }
        __syncthreads();
    }
}

/* ================= fallback tier: r6 multi-launch (proven 1550 us) ================= */
#define HS_PAR_FB 393216
__global__ __launch_bounds__(256) void ei_init3(const float* __restrict__ h0,
        float* __restrict__ out, float* __restrict__ v_ws, short* __restrict__ hfb){
    int idx = blockIdx.x * 256 + threadIdx.x;
    int l = idx >> 16, r = idx & 0xFFFF;
    float h = h0[r];
    out[OUT0_SZ + (size_t)l*ALLH_L + r] = h;
    v_ws[idx] = 0.f;
    if (idx < 24576){
        int lane = idx & 63, bt = (idx >> 6) & 3, kb = (idx >> 8) & 31, j = idx >> 13;
        int b = bt*16 + (lane & 15);
        int k = kb*32 + ((lane >> 4) << 3);
        const float* src = h0 + (size_t)b*HDIM + k;
        float4 v0 = *(const float4*)src;
        float4 v1 = *(const float4*)(src + 4);
        float f[8] = {v0.x,v0.y,v0.z,v0.w,v1.x,v1.y,v1.z,v1.w};
        bf16x8 hv, lv;
        #pragma unroll
        for (int e = 0; e < 8; ++e){
            short hh = f2bf(f[e]);
            hv[e] = hh; lv[e] = f2bf(f[e] - bf2f(hh));
        }
        int off = ((kb*4 + bt) << 9) + lane*8;
        short* b0 = hfb + (size_t)j*HS_LAY + off;
        *(bf16x8*)b0           = hv;
        *(bf16x8*)(b0 + 65536) = lv;
        short* b1 = b0 + HS_PAR_FB;
        *(bf16x8*)b1           = hv;
        *(bf16x8*)(b1 + 65536) = lv;
    }
}

template<int NKW, int NKFF, int FFLO>
__device__ __forceinline__ void stage_body5(
        const short* __restrict__ pff, const short* __restrict__ prec,
        const short* __restrict__ wp, int kb0, int laneo, f32x4 acc[4])
{
    bf16x8 wbh[NKW], wbl[NKW];
    #pragma unroll
    for (int kk = 0; kk < NKW; ++kk){
        const short* w0 = wp + ((kb0 + kk) << 10);
        wbh[kk] = *(const bf16x8*)w0;
        wbl[kk] = *(const bf16x8*)(w0 + 512);
    }
    bf16x8 ah[2][4], al[2][4];
    auto loadA = [&](int kk, int buf){
        int kb = kb0 + kk;
        const short* pa; int lo;
        if (kb < NKFF){ pa = pff + (kb << 11); lo = FFLO; }
        else          { pa = prec + ((kb - NKFF) << 11); lo = 65536; }
        #pragma unroll
        for (int bt = 0; bt < 4; ++bt){
            ah[buf][bt] = *(const bf16x8*)(pa + (bt << 9) + laneo);
            al[buf][bt] = *(const bf16x8*)(pa + lo + (bt << 9) + laneo);
        }
    };
    loadA(0, 0);
    #pragma unroll
    for (int kk = 0; kk < NKW; ++kk){
        if (kk + 1 < NKW) loadA(kk + 1, (kk + 1) & 1);
        const int bf = kk & 1;
        #pragma unroll
        for (int bt = 0; bt < 4; ++bt)
            acc[bt] = __builtin_amdgcn_mfma_f32_16x16x32_bf16(ah[bf][bt], wbh[kk], acc[bt], 0,0,0);
        #pragma unroll
        for (int bt = 0; bt < 4; ++bt)
            acc[bt] = __builtin_amdgcn_mfma_f32_16x16x32_bf16(al[bf][bt], wbh[kk], acc[bt], 0,0,0);
        #pragma unroll
        for (int bt = 0; bt < 4; ++bt)
            acc[bt] = __builtin_amdgcn_mfma_f32_16x16x32_bf16(ah[bf][bt], wbl[kk], acc[bt], 0,0,0);
    }
}

__global__ __launch_bounds__(512, 2) void ei_stage5(
        const short* __restrict__ xf, const short* __restrict__ wf,
        const float* __restrict__ bias, float* __restrict__ out,
        float* __restrict__ v_ws, short* __restrict__ hfb, int s)
{
    int j = blockIdx.x >> 6;
    int t = s - j;
    if (t < 0 || t >= T_STEPS) return;
    int it = blockIdx.x & 63;
    int wv = threadIdx.x >> 6, lane = threadIdx.x & 63;
    int laneo = lane * 8;
    int par_r = (s - 1) & 1, par_w = s & 1;
    const short* hfr  = hfb + par_r*HS_PAR_FB;
    const short* prec = hfr + j*HS_LAY;

    f32x4 acc[4] = {{0.f,0.f,0.f,0.f},{0.f,0.f,0.f,0.f},
                    {0.f,0.f,0.f,0.f},{0.f,0.f,0.f,0.f}};

    if (j == 0){
        const short* pff = xf + t*XF_T;
        const short* wp  = wf + it*48*1024 + laneo;
        stage_body5<6,16,32768>(pff, prec, wp, wv*6, laneo, acc);
    } else if (j == 1){
        const short* pff = hfr;
        const short* wp  = wf + 3145728 + it*64*1024 + laneo;
        stage_body5<8,32,65536>(pff, prec, wp, wv*8, laneo, acc);
    } else {
        const short* pff = hfr + HS_LAY;
        const short* wp  = wf + 7340032 + it*64*1024 + laneo;
        stage_body5<8,32,65536>(pff, prec, wp, wv*8, laneo, acc);
    }

    __shared__ float psum[8][64][18];
    {
        int r0 = (lane >> 4) << 2, l15 = lane & 15;
        #pragma unroll
        for (int bt = 0; bt < 4; ++bt)
            #pragma unroll
            for (int r = 0; r < 4; ++r)
                psum[wv][bt*16 + r0 + r][l15] = acc[bt][r];
    }
    __syncthreads();

    int tx  = threadIdx.x;
    int b   = tx >> 3;
    int il0 = (tx & 7) << 1;
    float* allh = out + OUT0_SZ + ((size_t)(j*129 + t + 1))*BH;
    float* outp = out + (size_t)t*BH;
    short* hww  = hfb + par_w*HS_PAR_FB + j*HS_LAY;
    float sum0 = 0.f, sum1 = 0.f;
    #pragma unroll
    for (int w = 0; w < 8; ++w){
        f32x2 p = *(f32x2*)&psum[w][b][il0];
        sum0 += p[0]; sum1 += p[1];
    }
    int i = it*16 + il0;
    f32x2 bb = *(const f32x2*)&bias[j*HDIM + i];
    int vo = (j*BATCH + b)*HDIM + i;
    f32x2 vold = *(f32x2*)&v_ws[vo];
    float vn0 = 0.8f * vold[0] + 0.2f * (sum0 + bb[0]);
    float vn1 = 0.8f * vold[1] + 0.2f * (sum1 + bb[1]);
    f32x2 vnv = {vn0, vn1};
    *(f32x2*)&v_ws[vo] = vnv;
    float h0 = vn0 > 0.f ? vn0 : 0.f;
    float h1 = vn1 > 0.f ? vn1 : 0.f;
    f32x2 hv2 = {h0, h1};
    *(f32x2*)&allh[b*HDIM + i] = hv2;
    short hh0 = f2bf(h0), hl0 = f2bf(h0 - bf2f(hh0));
    short hh1 = f2bf(h1), hl1 = f2bf(h1 - bf2f(hh1));
    int kb  = i >> 5, btw = b >> 4;
    int lnw = (b & 15) + (((i >> 3) & 3) << 4);
    int off = ((kb*4 + btw) << 9) + lnw*8 + (i & 7);
    short2v hi2 = {hh0, hh1}, lo2 = {hl0, hl1};
    *(short2v*)(hww + off)         = hi2;
    *(short2v*)(hww + off + 65536) = lo2;
    if (j == 2){
        f32x2 o2 = {(i < NE) ? h0 : 0.f, (i + 1 < NE) ? h1 : 0.f};
        *(f32x2*)&outp[b*HDIM + i] = o2;
    }
}

extern "C" void kernel_launch(void* const* d_in, const int* in_sizes, int n_in,
                              void* d_out, int out_size, void* d_ws, size_t ws_size,
                              hipStream_t stream) {
    const float* xin  = (const float*)d_in[0];
    const float* h0   = (const float*)d_in[1];
    const float* Win0 = (const float*)d_in[2];
    const float* Win1 = (const float*)d_in[3];
    const float* Win2 = (const float*)d_in[4];
    const float* Wrec = (const float*)d_in[5];
    const float* bias = (const float*)d_in[6];
    float* out  = (float*)d_out;
    char* ws    = (char*)d_ws;

    /* persistent layout: bar(65536) | hf(131*786432) | xf(16777216) | wf(23068672) */
    const size_t HF_B   = (size_t)NSLOT * HS_SLOT * 2ULL;            /* 103,022,592 */
    const size_t need_p = 65536 + HF_B + 16777216ULL + 23068672ULL;  /* 142,934,016 */

    if (ws_size >= need_p) {
        int*   bar = (int*)ws;
        short* hf  = (short*)(ws + 65536);
        short* xf  = (short*)(ws + 65536 + HF_B);
        short* wfp = (short*)(ws + 65536 + HF_B + 16777216ULL);
        hipLaunchKernelGGL(ei_prep_w, dim3(2816), dim3(256), 0, stream,
                           Win0, Win1, Win2, Wrec, wfp);
        hipLaunchKernelGGL(ei_prep_xf, dim3(2048), dim3(256), 0, stream, xin, xf);
        hipLaunchKernelGGL(ei_init5, dim3(768), dim3(256), 0, stream, h0, out, hf, bar);
        hipLaunchKernelGGL(ei_persist5, dim3(NBLK), dim3(512), 0, stream,
                           xf, wfp, bias, out, hf, bar);
    } else {
        float* v_ws = (float*)ws;
        short* hfb  = (short*)(ws + 786432);
        short* xf   = (short*)(ws + 786432 + 1572864ULL);
        short* wfp  = (short*)(ws + 786432 + 1572864ULL + 16777216ULL);
        hipLaunchKernelGGL(ei_prep_w, dim3(2816), dim3(256), 0, stream,
                           Win0, Win1, Win2, Wrec, wfp);
        hipLaunchKernelGGL(ei_prep_xf, dim3(2048), dim3(256), 0, stream, xin, xf);
        hipLaunchKernelGGL(ei_init3, dim3(768), dim3(256), 0, stream, h0, out, v_ws, hfb);
        for (int s = 0; s < T_STEPS + 2; ++s)
            hipLaunchKernelGGL(ei_stage5, dim3(192), dim3(512), 0, stream,
                               xf, wfp, bias, out, v_ws, hfb, s);
    }
}

// Round 12
// 1095.470 us; speedup vs baseline: 1.1035x; 1.1035x over previous
//
#include <hip/hip_runtime.h>

#define T_STEPS 128
#define BATCH   64
#define INDIM   512
#define HDIM    1024
#define NE      819
#define OUT0_SZ (T_STEPS*BATCH*HDIM)
#define BH      (BATCH*HDIM)          /* 65536 */
#define ALLH_L  (129*BH)

#define HS_LAY   131072               /* shorts per (slot,layer): hi 65536 + lo 65536 */
#define HS_SLOT  393216               /* shorts per slot (3 layers) */
#define NSLOT    131                  /* full-depth h ring: writes at s -> slot s+1 */
#define XF_T     65536                /* shorts per timestep of x-frags: hi 32768 + lo 32768 */
#define NBLK     192
#define NGRP     8
#define GSZ      24

typedef short bf16x8 __attribute__((ext_vector_type(8)));
typedef short short2v __attribute__((ext_vector_type(2)));
typedef float f32x4  __attribute__((ext_vector_type(4)));
typedef float f32x2  __attribute__((ext_vector_type(2)));

__device__ __forceinline__ short f2bf(float f){
    unsigned u = __float_as_uint(f);
    u += 0x7FFF + ((u >> 16) & 1);           /* RNE */
    return (short)(u >> 16);
}
__device__ __forceinline__ float bf2f(short s){
    return __uint_as_float(((unsigned)(unsigned short)s) << 16);
}

/* ============ one-time prep: weights -> |.|*sign*emask, split hi/lo, frag-swizzled ============ */
__global__ __launch_bounds__(256) void ei_prep_w(const float* __restrict__ Win0,
        const float* __restrict__ Win1, const float* __restrict__ Win2,
        const float* __restrict__ Wrec, short* __restrict__ wf){
    int gid = blockIdx.x * 256 + threadIdx.x;      /* 0 .. 720895 */
    int j, local, nkb, kff; const float* Win; short* base;
    if (gid < 196608)      { j=0; local=gid;        nkb=48; kff=512;  Win=Win0; base=wf; }
    else if (gid < 458752) { j=1; local=gid-196608; nkb=64; kff=1024; Win=Win1; base=wf+3145728; }
    else                   { j=2; local=gid-458752; nkb=64; kff=1024; Win=Win2; base=wf+7340032; }
    int lane = local & 63;
    int fi   = local >> 6;
    int kb   = fi % nkb;
    int it   = fi / nkb;
    int i    = it*16 + (lane & 15);
    int k0   = kb*32 + ((lane >> 4) << 3);
    const float* wrec_row = Wrec + ((size_t)j*HDIM + i)*HDIM;
    bf16x8 hv, lv;
    #pragma unroll
    for (int e = 0; e < 8; ++e){
        int k = k0 + e;
        float w;
        if (k < kff){
            w = fabsf(Win[(size_t)i*kff + k]);
            if (j != 0 && k >= NE) w = 0.f;
        } else {
            int kr = k - kff;
            w = fabsf(wrec_row[kr]);
            if (kr >= NE) w = -w;
        }
        short h = f2bf(w);
        hv[e] = h;
        lv[e] = f2bf(w - bf2f(h));
    }
    short* dst = base + (size_t)fi*1024 + lane*8;
    *(bf16x8*)dst         = hv;
    *(bf16x8*)(dst + 512) = lv;
}

/* ============ one-time prep: x -> A-frag layout [t][plane][kb(16)][bt(4)][lane(64)][8] ============ */
__global__ __launch_bounds__(256) void ei_prep_xf(const float* __restrict__ x,
        short* __restrict__ xf){
    int gid = blockIdx.x * 256 + threadIdx.x;      /* 0 .. 524287 */
    int lane = gid & 63;
    int bt   = (gid >> 6) & 3;
    int kb   = (gid >> 8) & 15;
    int t    = gid >> 12;
    int b = bt*16 + (lane & 15);
    int k = kb*32 + ((lane >> 4) << 3);
    const float* src = x + ((size_t)t*BATCH + b)*INDIM + k;
    float4 v0 = *(const float4*)src;
    float4 v1 = *(const float4*)(src + 4);
    float f[8] = {v0.x,v0.y,v0.z,v0.w,v1.x,v1.y,v1.z,v1.w};
    bf16x8 hv, lv;
    #pragma unroll
    for (int e = 0; e < 8; ++e){
        short h = f2bf(f[e]);
        hv[e] = h; lv[e] = f2bf(f[e] - bf2f(h));
    }
    short* dst = xf + (size_t)t*XF_T + (((size_t)(kb*4 + bt)) << 9) + lane*8;
    *(bf16x8*)dst            = hv;
    *(bf16x8*)(dst + 32768)  = lv;
}

/* ============ init: all_h[l][0]=h0, h-frag slot 0, barrier zero ============ */
__global__ __launch_bounds__(256) void ei_init5(const float* __restrict__ h0,
        float* __restrict__ out, short* __restrict__ hf, int* __restrict__ bar){
    int idx = blockIdx.x * 256 + threadIdx.x;      /* 0 .. 196607 */
    int l = idx >> 16, r = idx & 0xFFFF;
    out[OUT0_SZ + (size_t)l*ALLH_L + r] = h0[r];
    if (idx < 1024) bar[idx] = 0;
    if (idx < 24576){
        int lane = idx & 63, bt = (idx >> 6) & 3, kb = (idx >> 8) & 31, j = idx >> 13;
        int b = bt*16 + (lane & 15);
        int k = kb*32 + ((lane >> 4) << 3);
        const float* src = h0 + (size_t)b*HDIM + k;
        float4 v0 = *(const float4*)src;
        float4 v1 = *(const float4*)(src + 4);
        float f[8] = {v0.x,v0.y,v0.z,v0.w,v1.x,v1.y,v1.z,v1.w};
        bf16x8 hv, lv;
        #pragma unroll
        for (int e = 0; e < 8; ++e){
            short hh = f2bf(f[e]);
            hv[e] = hh; lv[e] = f2bf(f[e] - bf2f(hh));
        }
        int off = ((kb*4 + bt) << 9) + lane*8;
        short* b0 = hf + (size_t)j*HS_LAY + off;   /* slot 0 */
        *(bf16x8*)b0           = hv;
        *(bf16x8*)(b0 + 65536) = lv;
    }
}

/* ============ per-step GEMM body v4: A burst PINNED via sched_barrier(0) ============ */
template<int NKW, int NKFF, int FFLO>
__device__ __forceinline__ void step_mm4(
        const short* __restrict__ pff, const short* __restrict__ prec,
        const short* __restrict__ wp0, const short* __restrict__ wp1,
        int kb0, int btbase, int laneo, f32x4 acc[2][2])
{
    /* burst-issue ALL A fragments for this wave's K-slice */
    bf16x8 ah[NKW][2], al[NKW][2];
    #pragma unroll
    for (int kk = 0; kk < NKW; ++kk){
        int kb = kb0 + kk;
        const short* pa; int lo;
        if (kb < NKFF){ pa = pff + (kb << 11); lo = FFLO; }
        else          { pa = prec + ((kb - NKFF) << 11); lo = 65536; }
        ah[kk][0] = *(const bf16x8*)(pa + ((btbase + 0) << 9) + laneo);
        ah[kk][1] = *(const bf16x8*)(pa + ((btbase + 1) << 9) + laneo);
        al[kk][0] = *(const bf16x8*)(pa + lo + ((btbase + 0) << 9) + laneo);
        al[kk][1] = *(const bf16x8*)(pa + lo + ((btbase + 1) << 9) + laneo);
    }
    /* pin: nothing below may move above; loads above may not sink below */
    __builtin_amdgcn_sched_barrier(0);
    bf16x8 wh[2][2], wl[2][2];
    {
        const short* a = wp0 + (kb0 << 10);
        const short* b = wp1 + (kb0 << 10);
        wh[0][0] = *(const bf16x8*)a; wl[0][0] = *(const bf16x8*)(a + 512);
        wh[0][1] = *(const bf16x8*)b; wl[0][1] = *(const bf16x8*)(b + 512);
    }
    __builtin_amdgcn_sched_barrier(0);
    #pragma unroll
    for (int kk = 0; kk < NKW; ++kk){
        if (kk + 1 < NKW){
            const int nb = (kk + 1) & 1;
            const short* a = wp0 + ((kb0 + kk + 1) << 10);
            const short* b = wp1 + ((kb0 + kk + 1) << 10);
            wh[nb][0] = *(const bf16x8*)a; wl[nb][0] = *(const bf16x8*)(a + 512);
            wh[nb][1] = *(const bf16x8*)b; wl[nb][1] = *(const bf16x8*)(b + 512);
        }
        const int b2 = kk & 1;
        acc[0][0] = __builtin_amdgcn_mfma_f32_16x16x32_bf16(ah[kk][0], wh[b2][0], acc[0][0], 0,0,0);
        acc[0][1] = __builtin_amdgcn_mfma_f32_16x16x32_bf16(ah[kk][1], wh[b2][0], acc[0][1], 0,0,0);
        acc[1][0] = __builtin_amdgcn_mfma_f32_16x16x32_bf16(ah[kk][0], wh[b2][1], acc[1][0], 0,0,0);
        acc[1][1] = __builtin_amdgcn_mfma_f32_16x16x32_bf16(ah[kk][1], wh[b2][1], acc[1][1], 0,0,0);
        acc[0][0] = __builtin_amdgcn_mfma_f32_16x16x32_bf16(al[kk][0], wh[b2][0], acc[0][0], 0,0,0);
        acc[0][1] = __builtin_amdgcn_mfma_f32_16x16x32_bf16(al[kk][1], wh[b2][0], acc[0][1], 0,0,0);
        acc[1][0] = __builtin_amdgcn_mfma_f32_16x16x32_bf16(al[kk][0], wh[b2][1], acc[1][0], 0,0,0);
        acc[1][1] = __builtin_amdgcn_mfma_f32_16x16x32_bf16(al[kk][1], wh[b2][1], acc[1][1], 0,0,0);
        acc[0][0] = __builtin_amdgcn_mfma_f32_16x16x32_bf16(ah[kk][0], wl[b2][0], acc[0][0], 0,0,0);
        acc[0][1] = __builtin_amdgcn_mfma_f32_16x16x32_bf16(ah[kk][1], wl[b2][0], acc[0][1], 0,0,0);
        acc[1][0] = __builtin_amdgcn_mfma_f32_16x16x32_bf16(ah[kk][0], wl[b2][1], acc[1][0], 0,0,0);
        acc[1][1] = __builtin_amdgcn_mfma_f32_16x16x32_bf16(ah[kk][1], wl[b2][1], acc[1][1], 0,0,0);
    }
}

/* ============ persistent v6: r9 skeleton + pinned A burst + coalesced hf stores ===== */
__global__ __launch_bounds__(512, 2) void ei_persist6(
        const short* __restrict__ xf, const short* __restrict__ wf,
        const float* __restrict__ bias, float* __restrict__ out,
        short* __restrict__ hf, int* __restrict__ bar)
{
    const int bid   = blockIdx.x;
    const int g     = bid & 7;
    const int w     = bid >> 3;            /* 0..23 */
    const int j     = w >> 3;              /* 0..2 */
    const int strip = g*4 + ((w >> 1) & 3);/* 0..31 */
    const int bhalf = w & 1;
    const int grp   = g;

    const int tx    = threadIdx.x;
    const int wv    = tx >> 6, lane = tx & 63;
    const int laneo = lane * 8;
    const int btbase = bhalf * 2;
    const int it0   = strip * 2;

    const short* wfj = wf + (j == 0 ? 0 : (j == 1 ? 3145728 : 7340032));
    const int nkb  = (j == 0) ? 48 : 64;
    const int NKW  = nkb >> 3;
    const int kb0  = wv * NKW;
    const short* wp0 = wfj + it0*nkb*1024 + laneo;
    const short* wp1 = wp0 + nkb*1024;

    /* epilogue mapping, frag-linear for coalesced hf stores (r11, verified) */
    const int btl = tx >> 8;               /* 0..1 */
    const int q   = tx & 255;
    const int lnw = q >> 2;                /* 0..63 */
    const int e0  = (q & 3) * 2;           /* 0,2,4,6 */
    const int b_g = (bhalf*2 + btl)*16 + (lnw & 15);
    const int i_g = strip*32 + ((lnw >> 4) << 3) + e0;
    const int bl  = b_g & 31;
    const int il0 = ((lnw >> 4) << 3) + e0;
    const int hoff = ((strip*4 + bhalf*2 + btl) << 9) + q*2;   /* shorts */
    const f32x2 bb = *(const f32x2*)&bias[j*HDIM + i_g];
    f32x2 vreg = {0.f, 0.f};

    __shared__ float psum[8][32][34];

    for (int s = 0; s < T_STEPS + 2; ++s){
        const int t = s - j;
        const bool act = (t >= 0) && (t < T_STEPS);
        if (act){
            const short* hfr  = hf + (size_t)s*HS_SLOT;
            const short* prec = (t == 0) ? (hf + (size_t)j*HS_LAY)
                                         : (hfr + (size_t)j*HS_LAY);
            f32x4 acc[2][2] = {{{0.f,0.f,0.f,0.f},{0.f,0.f,0.f,0.f}},
                               {{0.f,0.f,0.f,0.f},{0.f,0.f,0.f,0.f}}};
            if (j == 0)
                step_mm4<6,16,32768>(xf + (size_t)t*XF_T, prec, wp0, wp1, kb0, btbase, laneo, acc);
            else if (j == 1)
                step_mm4<8,32,65536>(hfr, prec, wp0, wp1, kb0, btbase, laneo, acc);
            else
                step_mm4<8,32,65536>(hfr + HS_LAY, prec, wp0, wp1, kb0, btbase, laneo, acc);

            /* C/D layout: col=lane&15, row=(lane>>4)*4+r [m89] */
            const int r0 = (lane >> 4) << 2, l15 = lane & 15;
            #pragma unroll
            for (int ic = 0; ic < 2; ++ic)
                #pragma unroll
                for (int bt = 0; bt < 2; ++bt)
                    #pragma unroll
                    for (int r = 0; r < 4; ++r)
                        psum[wv][bt*16 + r0 + r][ic*16 + l15] = acc[ic][bt][r];
        }
        __syncthreads();
        if (act){
            float sum0 = 0.f, sum1 = 0.f;
            #pragma unroll
            for (int ww = 0; ww < 8; ++ww){
                f32x2 p = *(f32x2*)&psum[ww][bl][il0];
                sum0 += p[0]; sum1 += p[1];
            }
            vreg[0] = 0.8f*vreg[0] + 0.2f*(sum0 + bb[0]);
            vreg[1] = 0.8f*vreg[1] + 0.2f*(sum1 + bb[1]);
            float h0v = vreg[0] > 0.f ? vreg[0] : 0.f;
            float h1v = vreg[1] > 0.f ? vreg[1] : 0.f;
            f32x2 hv2 = {h0v, h1v};
            *(f32x2*)&out[OUT0_SZ + ((size_t)(j*129 + t + 1))*BH + b_g*HDIM + i_g] = hv2;
            if (j == 2){
                f32x2 o2 = {(i_g < NE) ? h0v : 0.f, (i_g + 1 < NE) ? h1v : 0.f};
                *(f32x2*)&out[(size_t)t*BH + b_g*HDIM + i_g] = o2;
            }
            /* h-frags: coalesced write-through (sc0 sc1) into virgin slot s+1 */
            short hh0 = f2bf(h0v), hl0 = f2bf(h0v - bf2f(hh0));
            short hh1 = f2bf(h1v), hl1 = f2bf(h1v - bf2f(hh1));
            int hi2 = (int)(unsigned short)hh0 | ((int)(unsigned short)hh1 << 16);
            int lo2 = (int)(unsigned short)hl0 | ((int)(unsigned short)hl1 << 16);
            short* hww = hf + (size_t)(s + 1)*HS_SLOT + (size_t)j*HS_LAY + hoff;
            asm volatile("global_store_dword %0, %1, off sc0 sc1"
                         :: "v"(hww), "v"(hi2) : "memory");
            asm volatile("global_store_dword %0, %1, off sc0 sc1"
                         :: "v"(hww + 65536), "v"(lo2) : "memory");
        }
        if (s == T_STEPS + 1) break;
        asm volatile("s_waitcnt vmcnt(0)" ::: "memory");
        __syncthreads();
        /* ---- relaxed two-level grid barrier (r9, proven) ---- */
        if (tx == 0){
            int prev = __hip_atomic_fetch_add(&bar[grp*32], 1,
                        __ATOMIC_RELAXED, __HIP_MEMORY_SCOPE_AGENT);
            if (prev == (s + 1)*GSZ - 1){
                int sp = __hip_atomic_fetch_add(&bar[256], 1,
                        __ATOMIC_RELAXED, __HIP_MEMORY_SCOPE_AGENT);
                if (sp == (s + 1)*NGRP - 1){
                    #pragma unroll
                    for (int gg = 0; gg < NGRP; ++gg)
                        __hip_atomic_store(&bar[512 + gg*32], s + 1,
                                __ATOMIC_RELAXED, __HIP_MEMORY_SCOPE_AGENT);
                }
            }
            while (__hip_atomic_load(&bar[512 + grp*32],
                    __ATOMIC_RELAXED, __HIP_MEMORY_SCOPE_AGENT) < s + 1)
                __builtin_amdgcn_s_sleep(1);
        }
        __syncthreads();
    }
}

/* ================= fallback tier: r6 multi-launch (proven 1550 us) ================= */
#define HS_PAR_FB 393216
__global__ __launch_bounds__(256) void ei_init3(const float* __restrict__ h0,
        float* __restrict__ out, float* __restrict__ v_ws, short* __restrict__ hfb){
    int idx = blockIdx.x * 256 + threadIdx.x;
    int l = idx >> 16, r = idx & 0xFFFF;
    float h = h0[r];
    out[OUT0_SZ + (size_t)l*ALLH_L + r] = h;
    v_ws[idx] = 0.f;
    if (idx < 24576){
        int lane = idx & 63, bt = (idx >> 6) & 3, kb = (idx >> 8) & 31, j = idx >> 13;
        int b = bt*16 + (lane & 15);
        int k = kb*32 + ((lane >> 4) << 3);
        const float* src = h0 + (size_t)b*HDIM + k;
        float4 v0 = *(const float4*)src;
        float4 v1 = *(const float4*)(src + 4);
        float f[8] = {v0.x,v0.y,v0.z,v0.w,v1.x,v1.y,v1.z,v1.w};
        bf16x8 hv, lv;
        #pragma unroll
        for (int e = 0; e < 8; ++e){
            short hh = f2bf(f[e]);
            hv[e] = hh; lv[e] = f2bf(f[e] - bf2f(hh));
        }
        int off = ((kb*4 + bt) << 9) + lane*8;
        short* b0 = hfb + (size_t)j*HS_LAY + off;
        *(bf16x8*)b0           = hv;
        *(bf16x8*)(b0 + 65536) = lv;
        short* b1 = b0 + HS_PAR_FB;
        *(bf16x8*)b1           = hv;
        *(bf16x8*)(b1 + 65536) = lv;
    }
}

template<int NKW, int NKFF, int FFLO>
__device__ __forceinline__ void stage_body5(
        const short* __restrict__ pff, const short* __restrict__ prec,
        const short* __restrict__ wp, int kb0, int laneo, f32x4 acc[4])
{
    bf16x8 wbh[NKW], wbl[NKW];
    #pragma unroll
    for (int kk = 0; kk < NKW; ++kk){
        const short* w0 = wp + ((kb0 + kk) << 10);
        wbh[kk] = *(const bf16x8*)w0;
        wbl[kk] = *(const bf16x8*)(w0 + 512);
    }
    bf16x8 ah[2][4], al[2][4];
    auto loadA = [&](int kk, int buf){
        int kb = kb0 + kk;
        const short* pa; int lo;
        if (kb < NKFF){ pa = pff + (kb << 11); lo = FFLO; }
        else          { pa = prec + ((kb - NKFF) << 11); lo = 65536; }
        #pragma unroll
        for (int bt = 0; bt < 4; ++bt){
            ah[buf][bt] = *(const bf16x8*)(pa + (bt << 9) + laneo);
            al[buf][bt] = *(const bf16x8*)(pa + lo + (bt << 9) + laneo);
        }
    };
    loadA(0, 0);
    #pragma unroll
    for (int kk = 0; kk < NKW; ++kk){
        if (kk + 1 < NKW) loadA(kk + 1, (kk + 1) & 1);
        const int bf = kk & 1;
        #pragma unroll
        for (int bt = 0; bt < 4; ++bt)
            acc[bt] = __builtin_amdgcn_mfma_f32_16x16x32_bf16(ah[bf][bt], wbh[kk], acc[bt], 0,0,0);
        #pragma unroll
        for (int bt = 0; bt < 4; ++bt)
            acc[bt] = __builtin_amdgcn_mfma_f32_16x16x32_bf16(al[bf][bt], wbh[kk], acc[bt], 0,0,0);
        #pragma unroll
        for (int bt = 0; bt < 4; ++bt)
            acc[bt] = __builtin_amdgcn_mfma_f32_16x16x32_bf16(ah[bf][bt], wbl[kk], acc[bt], 0,0,0);
    }
}

__global__ __launch_bounds__(512, 2) void ei_stage5(
        const short* __restrict__ xf, const short* __restrict__ wf,
        const float* __restrict__ bias, float* __restrict__ out,
        float* __restrict__ v_ws, short* __restrict__ hfb, int s)
{
    int j = blockIdx.x >> 6;
    int t = s - j;
    if (t < 0 || t >= T_STEPS) return;
    int it = blockIdx.x & 63;
    int wv = threadIdx.x >> 6, lane = threadIdx.x & 63;
    int laneo = lane * 8;
    int par_r = (s - 1) & 1, par_w = s & 1;
    const short* hfr  = hfb + par_r*HS_PAR_FB;
    const short* prec = hfr + j*HS_LAY;

    f32x4 acc[4] = {{0.f,0.f,0.f,0.f},{0.f,0.f,0.f,0.f},
                    {0.f,0.f,0.f,0.f},{0.f,0.f,0.f,0.f}};

    if (j == 0){
        const short* pff = xf + t*XF_T;
        const short* wp  = wf + it*48*1024 + laneo;
        stage_body5<6,16,32768>(pff, prec, wp, wv*6, laneo, acc);
    } else if (j == 1){
        const short* pff = hfr;
        const short* wp  = wf + 3145728 + it*64*1024 + laneo;
        stage_body5<8,32,65536>(pff, prec, wp, wv*8, laneo, acc);
    } else {
        const short* pff = hfr + HS_LAY;
        const short* wp  = wf + 7340032 + it*64*1024 + laneo;
        stage_body5<8,32,65536>(pff, prec, wp, wv*8, laneo, acc);
    }

    __shared__ float psum[8][64][18];
    {
        int r0 = (lane >> 4) << 2, l15 = lane & 15;
        #pragma unroll
        for (int bt = 0; bt < 4; ++bt)
            #pragma unroll
            for (int r = 0; r < 4; ++r)
                psum[wv][bt*16 + r0 + r][l15] = acc[bt][r];
    }
    __syncthreads();

    int tx  = threadIdx.x;
    int b   = tx >> 3;
    int il0 = (tx & 7) << 1;
    float* allh = out + OUT0_SZ + ((size_t)(j*129 + t + 1))*BH;
    float* outp = out + (size_t)t*BH;
    short* hww  = hfb + par_w*HS_PAR_FB + j*HS_LAY;
    float sum0 = 0.f, sum1 = 0.f;
    #pragma unroll
    for (int w = 0; w < 8; ++w){
        f32x2 p = *(f32x2*)&psum[w][b][il0];
        sum0 += p[0]; sum1 += p[1];
    }
    int i = it*16 + il0;
    f32x2 bb = *(const f32x2*)&bias[j*HDIM + i];
    int vo = (j*BATCH + b)*HDIM + i;
    f32x2 vold = *(f32x2*)&v_ws[vo];
    float vn0 = 0.8f * vold[0] + 0.2f * (sum0 + bb[0]);
    float vn1 = 0.8f * vold[1] + 0.2f * (sum1 + bb[1]);
    f32x2 vnv = {vn0, vn1};
    *(f32x2*)&v_ws[vo] = vnv;
    float h0 = vn0 > 0.f ? vn0 : 0.f;
    float h1 = vn1 > 0.f ? vn1 : 0.f;
    f32x2 hv2 = {h0, h1};
    *(f32x2*)&allh[b*HDIM + i] = hv2;
    short hh0 = f2bf(h0), hl0 = f2bf(h0 - bf2f(hh0));
    short hh1 = f2bf(h1), hl1 = f2bf(h1 - bf2f(hh1));
    int kb  = i >> 5, btw = b >> 4;
    int lnw = (b & 15) + (((i >> 3) & 3) << 4);
    int off = ((kb*4 + btw) << 9) + lnw*8 + (i & 7);
    short2v hi2 = {hh0, hh1}, lo2 = {hl0, hl1};
    *(short2v*)(hww + off)         = hi2;
    *(short2v*)(hww + off + 65536) = lo2;
    if (j == 2){
        f32x2 o2 = {(i < NE) ? h0 : 0.f, (i + 1 < NE) ? h1 : 0.f};
        *(f32x2*)&outp[b*HDIM + i] = o2;
    }
}

extern "C" void kernel_launch(void* const* d_in, const int* in_sizes, int n_in,
                              void* d_out, int out_size, void* d_ws, size_t ws_size,
                              hipStream_t stream) {
    const float* xin  = (const float*)d_in[0];
    const float* h0   = (const float*)d_in[1];
    const float* Win0 = (const float*)d_in[2];
    const float* Win1 = (const float*)d_in[3];
    const float* Win2 = (const float*)d_in[4];
    const float* Wrec = (const float*)d_in[5];
    const float* bias = (const float*)d_in[6];
    float* out  = (float*)d_out;
    char* ws    = (char*)d_ws;

    /* persistent layout: bar(65536) | hf(131*786432) | xf(16777216) | wf(23068672) */
    const size_t HF_B   = (size_t)NSLOT * HS_SLOT * 2ULL;            /* 103,022,592 */
    const size_t need_p = 65536 + HF_B + 16777216ULL + 23068672ULL;  /* 142,934,016 */

    if (ws_size >= need_p) {
        int*   bar = (int*)ws;
        short* hf  = (short*)(ws + 65536);
        short* xf  = (short*)(ws + 65536 + HF_B);
        short* wfp = (short*)(ws + 65536 + HF_B + 16777216ULL);
        hipLaunchKernelGGL(ei_prep_w, dim3(2816), dim3(256), 0, stream,
                           Win0, Win1, Win2, Wrec, wfp);
        hipLaunchKernelGGL(ei_prep_xf, dim3(2048), dim3(256), 0, stream, xin, xf);
        hipLaunchKernelGGL(ei_init5, dim3(768), dim3(256), 0, stream, h0, out, hf, bar);
        hipLaunchKernelGGL(ei_persist6, dim3(NBLK), dim3(512), 0, stream,
                           xf, wfp, bias, out, hf, bar);
    } else {
        float* v_ws = (float*)ws;
        short* hfb  = (short*)(ws + 786432);
        short* xf   = (short*)(ws + 786432 + 1572864ULL);
        short* wfp  = (short*)(ws + 786432 + 1572864ULL + 16777216ULL);
        hipLaunchKernelGGL(ei_prep_w, dim3(2816), dim3(256), 0, stream,
                           Win0, Win1, Win2, Wrec, wfp);
        hipLaunchKernelGGL(ei_prep_xf, dim3(2048), dim3(256), 0, stream, xin, xf);
        hipLaunchKernelGGL(ei_init3, dim3(768), dim3(256), 0, stream, h0, out, v_ws, hfb);
        for (int s = 0; s < T_STEPS + 2; ++s)
            hipLaunchKernelGGL(ei_stage5, dim3(192), dim3(512), 0, stream,
                               xf, wfp, bias, out, v_ws, hfb, s);
    }
}

// Round 13
// 1075.715 us; speedup vs baseline: 1.1238x; 1.0184x over previous
//
#include <hip/hip_runtime.h>

#define T_STEPS 128
#define BATCH   64
#define INDIM   512
#define HDIM    1024
#define NE      819
#define OUT0_SZ (T_STEPS*BATCH*HDIM)
#define BH      (BATCH*HDIM)          /* 65536 */
#define ALLH_L  (129*BH)

#define HS_LAY   131072               /* shorts per (slot,layer): hi 65536 + lo 65536 */
#define HS_SLOT  393216               /* shorts per slot (3 layers) */
#define NSLOT    131                  /* full-depth h ring: writes at s -> slot s+1 */
#define XF_T     65536                /* shorts per timestep of x-frags: hi 32768 + lo 32768 */
#define NBLK     192
#define NGRP     8
#define GSZ      24

typedef short bf16x8 __attribute__((ext_vector_type(8)));
typedef short short2v __attribute__((ext_vector_type(2)));
typedef float f32x4  __attribute__((ext_vector_type(4)));
typedef float f32x2  __attribute__((ext_vector_type(2)));

__device__ __forceinline__ short f2bf(float f){
    unsigned u = __float_as_uint(f);
    u += 0x7FFF + ((u >> 16) & 1);           /* RNE */
    return (short)(u >> 16);
}
__device__ __forceinline__ float bf2f(short s){
    return __uint_as_float(((unsigned)(unsigned short)s) << 16);
}

/* ============ one-time prep: weights -> |.|*sign*emask, split hi/lo, frag-swizzled ============ */
__global__ __launch_bounds__(256) void ei_prep_w(const float* __restrict__ Win0,
        const float* __restrict__ Win1, const float* __restrict__ Win2,
        const float* __restrict__ Wrec, short* __restrict__ wf){
    int gid = blockIdx.x * 256 + threadIdx.x;      /* 0 .. 720895 */
    int j, local, nkb, kff; const float* Win; short* base;
    if (gid < 196608)      { j=0; local=gid;        nkb=48; kff=512;  Win=Win0; base=wf; }
    else if (gid < 458752) { j=1; local=gid-196608; nkb=64; kff=1024; Win=Win1; base=wf+3145728; }
    else                   { j=2; local=gid-458752; nkb=64; kff=1024; Win=Win2; base=wf+7340032; }
    int lane = local & 63;
    int fi   = local >> 6;
    int kb   = fi % nkb;
    int it   = fi / nkb;
    int i    = it*16 + (lane & 15);
    int k0   = kb*32 + ((lane >> 4) << 3);
    const float* wrec_row = Wrec + ((size_t)j*HDIM + i)*HDIM;
    bf16x8 hv, lv;
    #pragma unroll
    for (int e = 0; e < 8; ++e){
        int k = k0 + e;
        float w;
        if (k < kff){
            w = fabsf(Win[(size_t)i*kff + k]);
            if (j != 0 && k >= NE) w = 0.f;
        } else {
            int kr = k - kff;
            w = fabsf(wrec_row[kr]);
            if (kr >= NE) w = -w;
        }
        short h = f2bf(w);
        hv[e] = h;
        lv[e] = f2bf(w - bf2f(h));
    }
    short* dst = base + (size_t)fi*1024 + lane*8;
    *(bf16x8*)dst         = hv;
    *(bf16x8*)(dst + 512) = lv;
}

/* ============ one-time prep: x -> A-frag layout [t][plane][kb(16)][bt(4)][lane(64)][8] ============ */
__global__ __launch_bounds__(256) void ei_prep_xf(const float* __restrict__ x,
        short* __restrict__ xf){
    int gid = blockIdx.x * 256 + threadIdx.x;      /* 0 .. 524287 */
    int lane = gid & 63;
    int bt   = (gid >> 6) & 3;
    int kb   = (gid >> 8) & 15;
    int t    = gid >> 12;
    int b = bt*16 + (lane & 15);
    int k = kb*32 + ((lane >> 4) << 3);
    const float* src = x + ((size_t)t*BATCH + b)*INDIM + k;
    float4 v0 = *(const float4*)src;
    float4 v1 = *(const float4*)(src + 4);
    float f[8] = {v0.x,v0.y,v0.z,v0.w,v1.x,v1.y,v1.z,v1.w};
    bf16x8 hv, lv;
    #pragma unroll
    for (int e = 0; e < 8; ++e){
        short h = f2bf(f[e]);
        hv[e] = h; lv[e] = f2bf(f[e] - bf2f(h));
    }
    short* dst = xf + (size_t)t*XF_T + (((size_t)(kb*4 + bt)) << 9) + lane*8;
    *(bf16x8*)dst            = hv;
    *(bf16x8*)(dst + 32768)  = lv;
}

/* ============ init: all_h[l][0]=h0, h-frag slot 0, barrier zero ============ */
__global__ __launch_bounds__(256) void ei_init5(const float* __restrict__ h0,
        float* __restrict__ out, short* __restrict__ hf, int* __restrict__ bar){
    int idx = blockIdx.x * 256 + threadIdx.x;      /* 0 .. 196607 */
    int l = idx >> 16, r = idx & 0xFFFF;
    out[OUT0_SZ + (size_t)l*ALLH_L + r] = h0[r];
    if (idx < 1024) bar[idx] = 0;
    if (idx < 24576){
        int lane = idx & 63, bt = (idx >> 6) & 3, kb = (idx >> 8) & 31, j = idx >> 13;
        int b = bt*16 + (lane & 15);
        int k = kb*32 + ((lane >> 4) << 3);
        const float* src = h0 + (size_t)b*HDIM + k;
        float4 v0 = *(const float4*)src;
        float4 v1 = *(const float4*)(src + 4);
        float f[8] = {v0.x,v0.y,v0.z,v0.w,v1.x,v1.y,v1.z,v1.w};
        bf16x8 hv, lv;
        #pragma unroll
        for (int e = 0; e < 8; ++e){
            short hh = f2bf(f[e]);
            hv[e] = hh; lv[e] = f2bf(f[e] - bf2f(hh));
        }
        int off = ((kb*4 + bt) << 9) + lane*8;
        short* b0 = hf + (size_t)j*HS_LAY + off;   /* slot 0 */
        *(bf16x8*)b0           = hv;
        *(bf16x8*)(b0 + 65536) = lv;
    }
}

/* ============ per-step GEMM body v4: A burst PINNED via sched_barrier(0) ============ */
template<int NKW, int NKFF, int FFLO>
__device__ __forceinline__ void step_mm4(
        const short* __restrict__ pff, const short* __restrict__ prec,
        const short* __restrict__ wp0, const short* __restrict__ wp1,
        int kb0, int btbase, int laneo, f32x4 acc[2][2])
{
    /* burst-issue ALL A fragments for this wave's K-slice */
    bf16x8 ah[NKW][2], al[NKW][2];
    #pragma unroll
    for (int kk = 0; kk < NKW; ++kk){
        int kb = kb0 + kk;
        const short* pa; int lo;
        if (kb < NKFF){ pa = pff + (kb << 11); lo = FFLO; }
        else          { pa = prec + ((kb - NKFF) << 11); lo = 65536; }
        ah[kk][0] = *(const bf16x8*)(pa + ((btbase + 0) << 9) + laneo);
        ah[kk][1] = *(const bf16x8*)(pa + ((btbase + 1) << 9) + laneo);
        al[kk][0] = *(const bf16x8*)(pa + lo + ((btbase + 0) << 9) + laneo);
        al[kk][1] = *(const bf16x8*)(pa + lo + ((btbase + 1) << 9) + laneo);
    }
    /* pin: nothing below may move above; loads above may not sink below */
    __builtin_amdgcn_sched_barrier(0);
    bf16x8 wh[2][2], wl[2][2];
    {
        const short* a = wp0 + (kb0 << 10);
        const short* b = wp1 + (kb0 << 10);
        wh[0][0] = *(const bf16x8*)a; wl[0][0] = *(const bf16x8*)(a + 512);
        wh[0][1] = *(const bf16x8*)b; wl[0][1] = *(const bf16x8*)(b + 512);
    }
    __builtin_amdgcn_sched_barrier(0);
    #pragma unroll
    for (int kk = 0; kk < NKW; ++kk){
        if (kk + 1 < NKW){
            const int nb = (kk + 1) & 1;
            const short* a = wp0 + ((kb0 + kk + 1) << 10);
            const short* b = wp1 + ((kb0 + kk + 1) << 10);
            wh[nb][0] = *(const bf16x8*)a; wl[nb][0] = *(const bf16x8*)(a + 512);
            wh[nb][1] = *(const bf16x8*)b; wl[nb][1] = *(const bf16x8*)(b + 512);
        }
        const int b2 = kk & 1;
        acc[0][0] = __builtin_amdgcn_mfma_f32_16x16x32_bf16(ah[kk][0], wh[b2][0], acc[0][0], 0,0,0);
        acc[0][1] = __builtin_amdgcn_mfma_f32_16x16x32_bf16(ah[kk][1], wh[b2][0], acc[0][1], 0,0,0);
        acc[1][0] = __builtin_amdgcn_mfma_f32_16x16x32_bf16(ah[kk][0], wh[b2][1], acc[1][0], 0,0,0);
        acc[1][1] = __builtin_amdgcn_mfma_f32_16x16x32_bf16(ah[kk][1], wh[b2][1], acc[1][1], 0,0,0);
        acc[0][0] = __builtin_amdgcn_mfma_f32_16x16x32_bf16(al[kk][0], wh[b2][0], acc[0][0], 0,0,0);
        acc[0][1] = __builtin_amdgcn_mfma_f32_16x16x32_bf16(al[kk][1], wh[b2][0], acc[0][1], 0,0,0);
        acc[1][0] = __builtin_amdgcn_mfma_f32_16x16x32_bf16(al[kk][0], wh[b2][1], acc[1][0], 0,0,0);
        acc[1][1] = __builtin_amdgcn_mfma_f32_16x16x32_bf16(al[kk][1], wh[b2][1], acc[1][1], 0,0,0);
        acc[0][0] = __builtin_amdgcn_mfma_f32_16x16x32_bf16(ah[kk][0], wl[b2][0], acc[0][0], 0,0,0);
        acc[0][1] = __builtin_amdgcn_mfma_f32_16x16x32_bf16(ah[kk][1], wl[b2][0], acc[0][1], 0,0,0);
        acc[1][0] = __builtin_amdgcn_mfma_f32_16x16x32_bf16(ah[kk][0], wl[b2][1], acc[1][0], 0,0,0);
        acc[1][1] = __builtin_amdgcn_mfma_f32_16x16x32_bf16(ah[kk][1], wl[b2][1], acc[1][1], 0,0,0);
    }
}

/* ============ persistent v7: all-thread flag polling (no tx0->syncthreads wake hop),
   arrival off critical path; r9 no-fence machinery unchanged ============ */
__global__ __launch_bounds__(512, 2) void ei_persist7(
        const short* __restrict__ xf, const short* __restrict__ wf,
        const float* __restrict__ bias, float* __restrict__ out,
        short* __restrict__ hf, int* __restrict__ bar)
{
    const int bid   = blockIdx.x;
    const int g     = bid & 7;
    const int w     = bid >> 3;            /* 0..23 */
    const int j     = w >> 3;              /* 0..2 */
    const int strip = g*4 + ((w >> 1) & 3);/* 0..31 */
    const int bhalf = w & 1;
    const int grp   = g;

    const int tx    = threadIdx.x;
    const int wv    = tx >> 6, lane = tx & 63;
    const int laneo = lane * 8;
    const int btbase = bhalf * 2;
    const int it0   = strip * 2;

    const short* wfj = wf + (j == 0 ? 0 : (j == 1 ? 3145728 : 7340032));
    const int nkb  = (j == 0) ? 48 : 64;
    const int NKW  = nkb >> 3;
    const int kb0  = wv * NKW;
    const short* wp0 = wfj + it0*nkb*1024 + laneo;
    const short* wp1 = wp0 + nkb*1024;

    /* epilogue mapping, frag-linear for coalesced hf stores (r11, verified) */
    const int btl = tx >> 8;               /* 0..1 */
    const int q   = tx & 255;
    const int lnw = q >> 2;                /* 0..63 */
    const int e0  = (q & 3) * 2;           /* 0,2,4,6 */
    const int b_g = (bhalf*2 + btl)*16 + (lnw & 15);
    const int i_g = strip*32 + ((lnw >> 4) << 3) + e0;
    const int bl  = b_g & 31;
    const int il0 = ((lnw >> 4) << 3) + e0;
    const int hoff = ((strip*4 + bhalf*2 + btl) << 9) + q*2;   /* shorts */
    const f32x2 bb = *(const f32x2*)&bias[j*HDIM + i_g];
    f32x2 vreg = {0.f, 0.f};

    __shared__ float psum[8][32][34];

    for (int s = 0; s < T_STEPS + 2; ++s){
        const int t = s - j;
        const bool act = (t >= 0) && (t < T_STEPS);
        /* ---- all-thread poll: wave wakes itself directly on the L3 flag.
           Same-address lanes coalesce to one request per wave; read-only line.
           Inactive blocks also poll (keeps arrival counts exact). ---- */
        if (s > 0){
            while (__hip_atomic_load(&bar[512 + grp*32],
                    __ATOMIC_RELAXED, __HIP_MEMORY_SCOPE_AGENT) < s)
                __builtin_amdgcn_s_sleep(1);
            asm volatile("" ::: "memory");          /* no load hoisting above poll */
            __builtin_amdgcn_sched_barrier(0);
        }
        if (act){
            const short* hfr  = hf + (size_t)s*HS_SLOT;
            const short* prec = (t == 0) ? (hf + (size_t)j*HS_LAY)
                                         : (hfr + (size_t)j*HS_LAY);
            f32x4 acc[2][2] = {{{0.f,0.f,0.f,0.f},{0.f,0.f,0.f,0.f}},
                               {{0.f,0.f,0.f,0.f},{0.f,0.f,0.f,0.f}}};
            if (j == 0)
                step_mm4<6,16,32768>(xf + (size_t)t*XF_T, prec, wp0, wp1, kb0, btbase, laneo, acc);
            else if (j == 1)
                step_mm4<8,32,65536>(hfr, prec, wp0, wp1, kb0, btbase, laneo, acc);
            else
                step_mm4<8,32,65536>(hfr + HS_LAY, prec, wp0, wp1, kb0, btbase, laneo, acc);

            /* C/D layout: col=lane&15, row=(lane>>4)*4+r [m89] */
            const int r0 = (lane >> 4) << 2, l15 = lane & 15;
            #pragma unroll
            for (int ic = 0; ic < 2; ++ic)
                #pragma unroll
                for (int bt = 0; bt < 2; ++bt)
                    #pragma unroll
                    for (int r = 0; r < 4; ++r)
                        psum[wv][bt*16 + r0 + r][ic*16 + l15] = acc[ic][bt][r];
        }
        __syncthreads();
        if (act){
            float sum0 = 0.f, sum1 = 0.f;
            #pragma unroll
            for (int ww = 0; ww < 8; ++ww){
                f32x2 p = *(f32x2*)&psum[ww][bl][il0];
                sum0 += p[0]; sum1 += p[1];
            }
            vreg[0] = 0.8f*vreg[0] + 0.2f*(sum0 + bb[0]);
            vreg[1] = 0.8f*vreg[1] + 0.2f*(sum1 + bb[1]);
            float h0v = vreg[0] > 0.f ? vreg[0] : 0.f;
            float h1v = vreg[1] > 0.f ? vreg[1] : 0.f;
            f32x2 hv2 = {h0v, h1v};
            *(f32x2*)&out[OUT0_SZ + ((size_t)(j*129 + t + 1))*BH + b_g*HDIM + i_g] = hv2;
            if (j == 2){
                f32x2 o2 = {(i_g < NE) ? h0v : 0.f, (i_g + 1 < NE) ? h1v : 0.f};
                *(f32x2*)&out[(size_t)t*BH + b_g*HDIM + i_g] = o2;
            }
            /* h-frags: coalesced write-through (sc0 sc1) into virgin slot s+1 */
            short hh0 = f2bf(h0v), hl0 = f2bf(h0v - bf2f(hh0));
            short hh1 = f2bf(h1v), hl1 = f2bf(h1v - bf2f(hh1));
            int hi2 = (int)(unsigned short)hh0 | ((int)(unsigned short)hh1 << 16);
            int lo2 = (int)(unsigned short)hl0 | ((int)(unsigned short)hl1 << 16);
            short* hww = hf + (size_t)(s + 1)*HS_SLOT + (size_t)j*HS_LAY + hoff;
            asm volatile("global_store_dword %0, %1, off sc0 sc1"
                         :: "v"(hww), "v"(hi2) : "memory");
            asm volatile("global_store_dword %0, %1, off sc0 sc1"
                         :: "v"(hww + 65536), "v"(lo2) : "memory");
        }
        if (s == T_STEPS + 1) break;
        /* drain own stores, block-consistent, then one arrival (off critical path:
           sibling waves advance to the next poll while tx0 does the atomics) */
        asm volatile("s_waitcnt vmcnt(0)" ::: "memory");
        __syncthreads();
        if (tx == 0){
            int prev = __hip_atomic_fetch_add(&bar[grp*32], 1,
                        __ATOMIC_RELAXED, __HIP_MEMORY_SCOPE_AGENT);
            if (prev == (s + 1)*GSZ - 1){
                int sp = __hip_atomic_fetch_add(&bar[256], 1,
                        __ATOMIC_RELAXED, __HIP_MEMORY_SCOPE_AGENT);
                if (sp == (s + 1)*NGRP - 1){
                    #pragma unroll
                    for (int gg = 0; gg < NGRP; ++gg)
                        __hip_atomic_store(&bar[512 + gg*32], s + 1,
                                __ATOMIC_RELAXED, __HIP_MEMORY_SCOPE_AGENT);
                }
            }
        }
    }
}

/* ================= fallback tier: r6 multi-launch (proven 1550 us) ================= */
#define HS_PAR_FB 393216
__global__ __launch_bounds__(256) void ei_init3(const float* __restrict__ h0,
        float* __restrict__ out, float* __restrict__ v_ws, short* __restrict__ hfb){
    int idx = blockIdx.x * 256 + threadIdx.x;
    int l = idx >> 16, r = idx & 0xFFFF;
    float h = h0[r];
    out[OUT0_SZ + (size_t)l*ALLH_L + r] = h;
    v_ws[idx] = 0.f;
    if (idx < 24576){
        int lane = idx & 63, bt = (idx >> 6) & 3, kb = (idx >> 8) & 31, j = idx >> 13;
        int b = bt*16 + (lane & 15);
        int k = kb*32 + ((lane >> 4) << 3);
        const float* src = h0 + (size_t)b*HDIM + k;
        float4 v0 = *(const float4*)src;
        float4 v1 = *(const float4*)(src + 4);
        float f[8] = {v0.x,v0.y,v0.z,v0.w,v1.x,v1.y,v1.z,v1.w};
        bf16x8 hv, lv;
        #pragma unroll
        for (int e = 0; e < 8; ++e){
            short hh = f2bf(f[e]);
            hv[e] = hh; lv[e] = f2bf(f[e] - bf2f(hh));
        }
        int off = ((kb*4 + bt) << 9) + lane*8;
        short* b0 = hfb + (size_t)j*HS_LAY + off;
        *(bf16x8*)b0           = hv;
        *(bf16x8*)(b0 + 65536) = lv;
        short* b1 = b0 + HS_PAR_FB;
        *(bf16x8*)b1           = hv;
        *(bf16x8*)(b1 + 65536) = lv;
    }
}

template<int NKW, int NKFF, int FFLO>
__device__ __forceinline__ void stage_body5(
        const short* __restrict__ pff, const short* __restrict__ prec,
        const short* __restrict__ wp, int kb0, int laneo, f32x4 acc[4])
{
    bf16x8 wbh[NKW], wbl[NKW];
    #pragma unroll
    for (int kk = 0; kk < NKW; ++kk){
        const short* w0 = wp + ((kb0 + kk) << 10);
        wbh[kk] = *(const bf16x8*)w0;
        wbl[kk] = *(const bf16x8*)(w0 + 512);
    }
    bf16x8 ah[2][4], al[2][4];
    auto loadA = [&](int kk, int buf){
        int kb = kb0 + kk;
        const short* pa; int lo;
        if (kb < NKFF){ pa = pff + (kb << 11); lo = FFLO; }
        else          { pa = prec + ((kb - NKFF) << 11); lo = 65536; }
        #pragma unroll
        for (int bt = 0; bt < 4; ++bt){
            ah[buf][bt] = *(const bf16x8*)(pa + (bt << 9) + laneo);
            al[buf][bt] = *(const bf16x8*)(pa + lo + (bt << 9) + laneo);
        }
    };
    loadA(0, 0);
    #pragma unroll
    for (int kk = 0; kk < NKW; ++kk){
        if (kk + 1 < NKW) loadA(kk + 1, (kk + 1) & 1);
        const int bf = kk & 1;
        #pragma unroll
        for (int bt = 0; bt < 4; ++bt)
            acc[bt] = __builtin_amdgcn_mfma_f32_16x16x32_bf16(ah[bf][bt], wbh[kk], acc[bt], 0,0,0);
        #pragma unroll
        for (int bt = 0; bt < 4; ++bt)
            acc[bt] = __builtin_amdgcn_mfma_f32_16x16x32_bf16(al[bf][bt], wbh[kk], acc[bt], 0,0,0);
        #pragma unroll
        for (int bt = 0; bt < 4; ++bt)
            acc[bt] = __builtin_amdgcn_mfma_f32_16x16x32_bf16(ah[bf][bt], wbl[kk], acc[bt], 0,0,0);
    }
}

__global__ __launch_bounds__(512, 2) void ei_stage5(
        const short* __restrict__ xf, const short* __restrict__ wf,
        const float* __restrict__ bias, float* __restrict__ out,
        float* __restrict__ v_ws, short* __restrict__ hfb, int s)
{
    int j = blockIdx.x >> 6;
    int t = s - j;
    if (t < 0 || t >= T_STEPS) return;
    int it = blockIdx.x & 63;
    int wv = threadIdx.x >> 6, lane = threadIdx.x & 63;
    int laneo = lane * 8;
    int par_r = (s - 1) & 1, par_w = s & 1;
    const short* hfr  = hfb + par_r*HS_PAR_FB;
    const short* prec = hfr + j*HS_LAY;

    f32x4 acc[4] = {{0.f,0.f,0.f,0.f},{0.f,0.f,0.f,0.f},
                    {0.f,0.f,0.f,0.f},{0.f,0.f,0.f,0.f}};

    if (j == 0){
        const short* pff = xf + t*XF_T;
        const short* wp  = wf + it*48*1024 + laneo;
        stage_body5<6,16,32768>(pff, prec, wp, wv*6, laneo, acc);
    } else if (j == 1){
        const short* pff = hfr;
        const short* wp  = wf + 3145728 + it*64*1024 + laneo;
        stage_body5<8,32,65536>(pff, prec, wp, wv*8, laneo, acc);
    } else {
        const short* pff = hfr + HS_LAY;
        const short* wp  = wf + 7340032 + it*64*1024 + laneo;
        stage_body5<8,32,65536>(pff, prec, wp, wv*8, laneo, acc);
    }

    __shared__ float psum[8][64][18];
    {
        int r0 = (lane >> 4) << 2, l15 = lane & 15;
        #pragma unroll
        for (int bt = 0; bt < 4; ++bt)
            #pragma unroll
            for (int r = 0; r < 4; ++r)
                psum[wv][bt*16 + r0 + r][l15] = acc[bt][r];
    }
    __syncthreads();

    int tx  = threadIdx.x;
    int b   = tx >> 3;
    int il0 = (tx & 7) << 1;
    float* allh = out + OUT0_SZ + ((size_t)(j*129 + t + 1))*BH;
    float* outp = out + (size_t)t*BH;
    short* hww  = hfb + par_w*HS_PAR_FB + j*HS_LAY;
    float sum0 = 0.f, sum1 = 0.f;
    #pragma unroll
    for (int w = 0; w < 8; ++w){
        f32x2 p = *(f32x2*)&psum[w][b][il0];
        sum0 += p[0]; sum1 += p[1];
    }
    int i = it*16 + il0;
    f32x2 bb = *(const f32x2*)&bias[j*HDIM + i];
    int vo = (j*BATCH + b)*HDIM + i;
    f32x2 vold = *(f32x2*)&v_ws[vo];
    float vn0 = 0.8f * vold[0] + 0.2f * (sum0 + bb[0]);
    float vn1 = 0.8f * vold[1] + 0.2f * (sum1 + bb[1]);
    f32x2 vnv = {vn0, vn1};
    *(f32x2*)&v_ws[vo] = vnv;
    float h0 = vn0 > 0.f ? vn0 : 0.f;
    float h1 = vn1 > 0.f ? vn1 : 0.f;
    f32x2 hv2 = {h0, h1};
    *(f32x2*)&allh[b*HDIM + i] = hv2;
    short hh0 = f2bf(h0), hl0 = f2bf(h0 - bf2f(hh0));
    short hh1 = f2bf(h1), hl1 = f2bf(h1 - bf2f(hh1));
    int kb  = i >> 5, btw = b >> 4;
    int lnw = (b & 15) + (((i >> 3) & 3) << 4);
    int off = ((kb*4 + btw) << 9) + lnw*8 + (i & 7);
    short2v hi2 = {hh0, hh1}, lo2 = {hl0, hl1};
    *(short2v*)(hww + off)         = hi2;
    *(short2v*)(hww + off + 65536) = lo2;
    if (j == 2){
        f32x2 o2 = {(i < NE) ? h0 : 0.f, (i + 1 < NE) ? h1 : 0.f};
        *(f32x2*)&outp[b*HDIM + i] = o2;
    }
}

extern "C" void kernel_launch(void* const* d_in, const int* in_sizes, int n_in,
                              void* d_out, int out_size, void* d_ws, size_t ws_size,
                              hipStream_t stream) {
    const float* xin  = (const float*)d_in[0];
    const float* h0   = (const float*)d_in[1];
    const float* Win0 = (const float*)d_in[2];
    const float* Win1 = (const float*)d_in[3];
    const float* Win2 = (const float*)d_in[4];
    const float* Wrec = (const float*)d_in[5];
    const float* bias = (const float*)d_in[6];
    float* out  = (float*)d_out;
    char* ws    = (char*)d_ws;

    /* persistent layout: bar(65536) | hf(131*786432) | xf(16777216) | wf(23068672) */
    const size_t HF_B   = (size_t)NSLOT * HS_SLOT * 2ULL;            /* 103,022,592 */
    const size_t need_p = 65536 + HF_B + 16777216ULL + 23068672ULL;  /* 142,934,016 */

    if (ws_size >= need_p) {
        int*   bar = (int*)ws;
        short* hf  = (short*)(ws + 65536);
        short* xf  = (short*)(ws + 65536 + HF_B);
        short* wfp = (short*)(ws + 65536 + HF_B + 16777216ULL);
        hipLaunchKernelGGL(ei_prep_w, dim3(2816), dim3(256), 0, stream,
                           Win0, Win1, Win2, Wrec, wfp);
        hipLaunchKernelGGL(ei_prep_xf, dim3(2048), dim3(256), 0, stream, xin, xf);
        hipLaunchKernelGGL(ei_init5, dim3(768), dim3(256), 0, stream, h0, out, hf, bar);
        hipLaunchKernelGGL(ei_persist7, dim3(NBLK), dim3(512), 0, stream,
                           xf, wfp, bias, out, hf, bar);
    } else {
        float* v_ws = (float*)ws;
        short* hfb  = (short*)(ws + 786432);
        short* xf   = (short*)(ws + 786432 + 1572864ULL);
        short* wfp  = (short*)(ws + 786432 + 1572864ULL + 16777216ULL);
        hipLaunchKernelGGL(ei_prep_w, dim3(2816), dim3(256), 0, stream,
                           Win0, Win1, Win2, Wrec, wfp);
        hipLaunchKernelGGL(ei_prep_xf, dim3(2048), dim3(256), 0, stream, xin, xf);
        hipLaunchKernelGGL(ei_init3, dim3(768), dim3(256), 0, stream, h0, out, v_ws, hfb);
        for (int s = 0; s < T_STEPS + 2; ++s)
            hipLaunchKernelGGL(ei_stage5, dim3(192), dim3(512), 0, stream,
                               xf, wfp, bias, out, v_ws, hfb, s);
    }
}